// Round 1
// baseline (46.712 us; speedup 1.0000x reference)
//
#include <hip/hip_runtime.h>

#define K_HP 0.0244f
#define I_THRESH 0.39063f

// tanh(v) = 1 - 2/(1+exp(2v)); NaN-free at both extremes:
//   v -> +inf: exp -> inf, rcp -> 0, result 1
//   v -> -inf: exp -> 0,   rcp -> 1, result -1
__device__ __forceinline__ float tanh_fast(float v) {
    float e = __expf(2.0f * v);                       // v_exp_f32 path
    float r = __builtin_amdgcn_rcpf(1.0f + e);        // v_rcp_f32, ~1 ulp
    return fmaf(-2.0f, r, 1.0f);
}

__global__ __launch_bounds__(256) void pid_kernel(
    const float* __restrict__ x,
    const float* __restrict__ last,
    const float* __restrict__ w1, const float* __restrict__ b1,
    const float* __restrict__ w2, const float* __restrict__ b2,
    const float* __restrict__ w3, const float* __restrict__ b3,
    float* __restrict__ out, int n)
{
    // Wave-uniform weight loads -> scalar loads, hoisted out of the loop.
    float W1[8], B1[8], W2[64], B2[8], W3[8];
    #pragma unroll
    for (int j = 0; j < 8; ++j) { W1[j] = w1[j]; B1[j] = b1[j]; B2[j] = b2[j]; W3[j] = w3[j]; }
    #pragma unroll
    for (int j = 0; j < 64; ++j) W2[j] = w2[j];
    const float B3 = b3[0];

    const float a   = 0.3417968f;   // interior PID_KP value
    const float Kic = 0.1503906f;   // PID_KI is constant everywhere

    int idx    = blockIdx.x * blockDim.x + threadIdx.x;
    int stride = gridDim.x * blockDim.x;
    for (int i = idx; i < n; i += stride) {
        const float* row = x + (size_t)i * 13;
        float hi   = row[5];
        float aim  = row[7];
        float rate = row[11];

        float d_raw = aim - hi;
        float diff  = d_raw * K_HP;

        // MLP 1->8->8->1
        float h1[8];
        #pragma unroll
        for (int j = 0; j < 8; ++j) h1[j] = tanh_fast(fmaf(diff, W1[j], B1[j]));
        float k_out = B3;
        #pragma unroll
        for (int j = 0; j < 8; ++j) {
            float acc = B2[j];
            #pragma unroll
            for (int k = 0; k < 8; ++k) acc = fmaf(h1[k], W2[k * 8 + j], acc);
            k_out = fmaf(tanh_fast(acc), W3[j], k_out);
        }
        float diff_real = d_raw * k_out;

        // Kp interp: symmetric in diff; constant a on [-2.5,2.5], lerp to 0.5 at +-10
        float ad = fabsf(diff);
        float t  = fminf(fmaxf((ad - 2.5f) * (1.0f / 7.5f), 0.0f), 1.0f);
        float Kp = fmaf(t, 0.5f - a, a) * rate;
        float Ki = Kic * rate;

        float ivalue = (ad < I_THRESH) ? 0.0f : diff_real * 0.5f;
        out[i] = last[i] + fmaf(Ki, ivalue, Kp * diff_real);
    }
}

extern "C" void kernel_launch(void* const* d_in, const int* in_sizes, int n_in,
                              void* d_out, int out_size, void* d_ws, size_t ws_size,
                              hipStream_t stream) {
    const float* x    = (const float*)d_in[0];
    const float* last = (const float*)d_in[1];
    const float* w1   = (const float*)d_in[2];
    const float* b1   = (const float*)d_in[3];
    const float* w2   = (const float*)d_in[4];
    const float* b2   = (const float*)d_in[5];
    const float* w3   = (const float*)d_in[6];
    const float* b3   = (const float*)d_in[7];
    float* out = (float*)d_out;
    int n = out_size;
    pid_kernel<<<2048, 256, 0, stream>>>(x, last, w1, b1, w2, b2, w3, b3, out, n);
}